// Round 14
// baseline (3163.800 us; speedup 1.0000x reference)
//
#include <hip/hip_runtime.h>

#define NXg 512
#define NYg 512
#define NNg (NXg*NYg)
#define TPB 512
#define NBT 256
#define BCOLS 4
#define BROWS 64
#define TW 128          // tile width (cols)
#define TH 8            // tile height (rows)
#define NSTEPS 8
#define CGIT 10
#define DTf (1.0f/64.0f)
#define H2I 256.0f

// ws float layout — cross-block via relaxed AGENT (sc1) atomics only, no fences.
//  [b*16], b<256        arrival flags (int)
//  [4096 + l*16], l<64  release lines (int)
//  [6144 .. 6272)       global scalars: [par][2 phase][16]
//  [8192 .. 16384)      parts[2 par][256 block][16 metric]
//  [16384 ..)           R[4ch][NNg]  (boundary cells only used)
#define REL_OFF     4096
#define SCAL_OFF    6144
#define PARTS_OFF   8192
#define CTRL_FLOATS 16384
#define R_OFF(c)    (CTRL_FLOATS + (c)*NNg)

__device__ __forceinline__ int ld_flag(int* p){
  return __hip_atomic_load(p, __ATOMIC_RELAXED, __HIP_MEMORY_SCOPE_AGENT);
}
__device__ __forceinline__ void st_flag(int* p, int v){
  __hip_atomic_store(p, v, __ATOMIC_RELAXED, __HIP_MEMORY_SCOPE_AGENT);
}
__device__ __forceinline__ float ldg1(float* p){
  return __hip_atomic_load(p, __ATOMIC_RELAXED, __HIP_MEMORY_SCOPE_AGENT);
}
__device__ __forceinline__ void stg1(float* p, float v){
  __hip_atomic_store(p, v, __ATOMIC_RELAXED, __HIP_MEMORY_SCOPE_AGENT);
}
union F2U { unsigned long long u; float2 f; };
__device__ __forceinline__ float2 ldg2(float* p){
  F2U t; t.u = __hip_atomic_load((unsigned long long*)p, __ATOMIC_RELAXED, __HIP_MEMORY_SCOPE_AGENT);
  return t.f;
}
__device__ __forceinline__ void stg2(float* p, float2 v){
  F2U t; t.f = v;
  __hip_atomic_store((unsigned long long*)p, t.u, __ATOMIC_RELAXED, __HIP_MEMORY_SCOPE_AGENT);
}

// plain fence-free barrier (step boundary): r13-proven protocol
__device__ __forceinline__ void gsync(int* wsi, int bid, int tid, int tgt){
  asm volatile("s_waitcnt vmcnt(0)" ::: "memory");
  __syncthreads();
  if (tid==0) st_flag(&wsi[bid*16], tgt);
  if (bid==0 && tid<64){
    int ok=0;
    while(!ok){
      int m=1;
      #pragma unroll
      for (int j=0;j<4;++j) m &= (ld_flag(&wsi[(tid+64*j)*16]) >= tgt);
      ok=__all(m);
      if(!ok) __builtin_amdgcn_s_sleep(1);
    }
    st_flag(&wsi[REL_OFF + tid*16], tgt);
  }
  if (tid==0){
    int* rl = &wsi[REL_OFF + (bid&63)*16];
    while(ld_flag(rl) < tgt) __builtin_amdgcn_s_sleep(1);
  }
  __syncthreads();
}

// barrier + master-folded global reduce: block partials already in
// parts[bid*16 + MB .. +NM); master (block0 wave0) sums all 256 blocks,
// stores NM scalars at scal, vmcnt-drains, releases; waiters read scalars.
template<int NM, int MB>
__device__ __forceinline__ void gsync_red(int* wsi, float* parts, float* scal,
                                          float* sRedDst, int bid, int tid, int tgt){
  asm volatile("s_waitcnt vmcnt(0)" ::: "memory");
  __syncthreads();
  if (tid==0) st_flag(&wsi[bid*16], tgt);
  if (bid==0 && tid<64){
    int ok=0;
    while(!ok){
      int m=1;
      #pragma unroll
      for (int j=0;j<4;++j) m &= (ld_flag(&wsi[(tid+64*j)*16]) >= tgt);
      ok=__all(m);
      if(!ok) __builtin_amdgcn_s_sleep(1);
    }
    float acc[NM];
    #pragma unroll
    for (int m=0;m<NM;++m) acc[m]=0.f;
    #pragma unroll
    for (int b4=0;b4<4;++b4){
      const int b = tid*4 + b4;
      #pragma unroll
      for (int m=0;m<NM;m+=2){
        const float2 v = ldg2(parts + b*16 + MB + m);
        acc[m] += v.x; acc[m+1] += v.y;
      }
    }
    #pragma unroll
    for (int m=0;m<NM;++m){
      float v=acc[m];
      #pragma unroll
      for (int off=32; off; off>>=1) v += __shfl_xor(v, off);
      acc[m]=v;
    }
    if (tid==0){
      #pragma unroll
      for (int m=0;m<NM;m+=2) stg2(scal + m, make_float2(acc[m],acc[m+1]));
    }
    asm volatile("s_waitcnt vmcnt(0)" ::: "memory");  // scalars before release
    st_flag(&wsi[REL_OFF + tid*16], tgt);
  }
  if (tid==0){
    int* rl = &wsi[REL_OFF + (bid&63)*16];
    while(ld_flag(rl) < tgt) __builtin_amdgcn_s_sleep(1);
  }
  __syncthreads();
  if (tid < NM/2){
    const float2 v = ldg2(scal + 2*tid);
    sRedDst[2*tid] = v.x; sRedDst[2*tid+1] = v.y;
  }
  __syncthreads();
}

__device__ __forceinline__ void mlp_all(const float* sW, const float* vv, float* o){
  float h1[16];
  #pragma unroll
  for (int h=0;h<16;++h)
    h1[h] = tanhf(vv[0]*sW[h]+vv[1]*sW[16+h]+vv[2]*sW[32+h]+vv[3]*sW[48+h]);
  o[0]=o[1]=o[2]=o[3]=0.f;
  #pragma unroll
  for (int j=0;j<16;++j){
    float s=0.f;
    #pragma unroll
    for (int h=0;h<16;++h) s += h1[h]*sW[64+16*h+j];
    const float t = tanhf(s);
    o[0]+=t*sW[320+4*j+0]; o[1]+=t*sW[320+4*j+1];
    o[2]+=t*sW[320+4*j+2]; o[3]+=t*sW[320+4*j+3];
  }
}

__global__ void __launch_bounds__(TPB)
drk(const float* __restrict__ U0, const float* __restrict__ scale,
    const float* __restrict__ K1, const float* __restrict__ K2,
    const float* __restrict__ K3, float* __restrict__ out,
    float* __restrict__ ws)
{
  __shared__ float sW[384];
  __shared__ float sP[TH][4][TW];   // pn tile, 16 KB
  __shared__ float wRed[8][8];
  __shared__ float sRed[12];

  const int tid=threadIdx.x, bid=blockIdx.x;
  const int lr   = tid>>6;          // local row 0..7
  const int lane = tid&63;
  const int wv   = tid>>6;          // wave == local row here
  const int lc2  = lane*2;          // local col base (2 cells/thread)
  const int bx   = bid & 3, by = bid >> 2;
  const int grow = by*TH + lr;
  const int gcol = bx*TW + lc2;
  const int cell0= grow*NXg + gcol;
  const bool topT = (lr==0), botT = (lr==TH-1);
  const bool hV   = (topT && by>0) || (botT && by<BROWS-1);  // has vert halo
  const int  hrow = topT ? (grow-1) : (grow+1);
  const bool pubRow = hV;                                    // publishes own row
  const bool westT = (lane==0), eastT = (lane==63);
  const bool hW = westT && bx>0;
  const bool hE = eastT && bx<BCOLS-1;

  if (tid < 384){
    float w;
    if (tid < 64)       w = K1[tid];
    else if (tid < 320) w = K2[tid-64];
    else                w = K3[tid-320];
    sW[tid]=w;
  }
  __syncthreads();

  int* wsi = (int*)ws;
  float gam[4];
  #pragma unroll
  for (int c=0;c<4;++c) gam[c] = 1.0f/(scale[c]*DTf);

  float xnew[2][4];
  {
    const float4 u0 = ((const float4*)U0)[cell0];
    const float4 u1 = ((const float4*)U0)[cell0+1];
    xnew[0][0]=u0.x; xnew[0][1]=u0.y; xnew[0][2]=u0.z; xnew[0][3]=u0.w;
    xnew[1][0]=u1.x; xnew[1][1]=u1.y; xnew[1][2]=u1.z; xnew[1][3]=u1.w;
  }

  for (int step=0; step<NSTEPS; ++step){
    float rr[2][4], xx[2][4], pold[2][4];
    float pnhV[2][4], pnhW[4], pnhE[4];
    float alpha[4], beta[4], rs[4], bb[4];
    #pragma unroll
    for (int c=0;c<4;++c){
      bb[c]=0.f; beta[c]=0.f; pnhW[c]=0.f; pnhE[c]=0.f;
      #pragma unroll
      for (int k=0;k<2;++k){
        rr[k][c] = gam[c]*xnew[k][c];
        bb[c]   += rr[k][c]*rr[k][c];
        xx[k][c]=0.f; pold[k][c]=0.f; pnhV[k][c]=0.f;
      }
    }

    for (int it=0; it<CGIT; ++it){
      const int g = step*CGIT + it;
      const int par = g&1;
      float* parts = ws + PARTS_OFF + par*4096;
      float* scalA = ws + SCAL_OFF + par*32;
      float* scalB = scalA + 16;

      // ---- phase A: pn = r + beta*p_old; LDS tile; halo mirrors ----
      float pn[2][4], Ap[2][4];
      #pragma unroll
      for (int k=0;k<2;++k)
      #pragma unroll
      for (int c=0;c<4;++c){
        pn[k][c] = rr[k][c] + beta[c]*pold[k][c];
        sP[lr][c][lc2+k] = pn[k][c];
      }

      // mirrors: pnh(it) = r_h(it) + beta*pnh(it-1)
      if (step==0 && it==0){
        if (hV){
          const float4 h0 = ((const float4*)U0)[hrow*NXg + gcol];
          const float4 h1 = ((const float4*)U0)[hrow*NXg + gcol + 1];
          pnhV[0][0]=gam[0]*h0.x; pnhV[0][1]=gam[1]*h0.y; pnhV[0][2]=gam[2]*h0.z; pnhV[0][3]=gam[3]*h0.w;
          pnhV[1][0]=gam[0]*h1.x; pnhV[1][1]=gam[1]*h1.y; pnhV[1][2]=gam[2]*h1.z; pnhV[1][3]=gam[3]*h1.w;
        }
        if (hW){
          const float4 h = ((const float4*)U0)[grow*NXg + gcol - 1];
          pnhW[0]=gam[0]*h.x; pnhW[1]=gam[1]*h.y; pnhW[2]=gam[2]*h.z; pnhW[3]=gam[3]*h.w;
        }
        if (hE){
          const float4 h = ((const float4*)U0)[grow*NXg + gcol + 2];
          pnhE[0]=gam[0]*h.x; pnhE[1]=gam[1]*h.y; pnhE[2]=gam[2]*h.z; pnhE[3]=gam[3]*h.w;
        }
      } else {
        if (hV){
          #pragma unroll
          for (int c=0;c<4;++c){
            const float2 h = ldg2(ws + R_OFF(c) + hrow*NXg + gcol);
            pnhV[0][c] = h.x + beta[c]*pnhV[0][c];
            pnhV[1][c] = h.y + beta[c]*pnhV[1][c];
          }
        }
        if (hW){
          #pragma unroll
          for (int c=0;c<4;++c)
            pnhW[c] = ldg1(ws + R_OFF(c) + grow*NXg + gcol - 1) + beta[c]*pnhW[c];
        }
        if (hE){
          #pragma unroll
          for (int c=0;c<4;++c)
            pnhE[c] = ldg1(ws + R_OFF(c) + grow*NXg + gcol + 2) + beta[c]*pnhE[c];
        }
      }
      __syncthreads();   // sP tile complete

      // ---- stencil + pAp partials ----
      float pap[4]={0,0,0,0};
      #pragma unroll
      for (int c=0;c<4;++c)
      #pragma unroll
      for (int k=0;k<2;++k){
        const float u = pn[k][c];
        float s = 0.f;
        if (lr>0)          s += u - sP[lr-1][c][lc2+k];
        else if (by>0)     s += u - pnhV[k][c];
        if (lr<TH-1)       s += u - sP[lr+1][c][lc2+k];
        else if (by<BROWS-1) s += u - pnhV[k][c];
        if (k==1)          s += u - pn[0][c];
        else if (lc2>0)    s += u - sP[lr][c][lc2-1];
        else if (bx>0)     s += u - pnhW[c];
        if (k==0)          s += u - pn[1][c];
        else if (lc2<TW-2) s += u - sP[lr][c][lc2+2];
        else if (bx<BCOLS-1) s += u - pnhE[c];
        const float ap = s*H2I + gam[c]*u;
        Ap[k][c] = ap;
        pap[c]  += u*ap;
      }

      // block-reduce 8 metrics {pAp[4], bb[4]} -> parts[bid][0..7]
      {
        float m8[8];
        #pragma unroll
        for (int c=0;c<4;++c){ m8[c]=pap[c]; m8[4+c]=bb[c]; }
        #pragma unroll
        for (int m=0;m<8;++m){
          float v=m8[m];
          #pragma unroll
          for (int off=32; off; off>>=1) v += __shfl_xor(v, off);
          m8[m]=v;
        }
        if (lane==0){
          #pragma unroll
          for (int m=0;m<8;++m) wRed[wv][m]=m8[m];
        }
        __syncthreads();
        if (tid<4){
          float s0=0.f, s1=0.f;
          #pragma unroll
          for (int w=0;w<8;++w){ s0 += wRed[w][2*tid]; s1 += wRed[w][2*tid+1]; }
          stg2(parts + bid*16 + 2*tid, make_float2(s0,s1));
        }
      }
      gsync_red<8,0>(wsi, parts, scalA, sRed, bid, tid, 2*g+1);

      #pragma unroll
      for (int c=0;c<4;++c){
        if (it==0) rs[c] = sRed[4+c];
        alpha[c] = rs[c]/sRed[c];
      }
      #pragma unroll
      for (int k=0;k<2;++k)
      #pragma unroll
      for (int c=0;c<4;++c){
        xx[k][c] += alpha[c]*pn[k][c];
        rr[k][c] -= alpha[c]*Ap[k][c];
      }

      if (it < CGIT-1){
        // ---- phase B: publish boundary r; DIRECT Σr² via master-fold ----
        if (pubRow){
          #pragma unroll
          for (int c=0;c<4;++c)
            stg2(ws + R_OFF(c) + cell0, make_float2(rr[0][c],rr[1][c]));
        }
        if (hW && !pubRow){
          #pragma unroll
          for (int c=0;c<4;++c) stg1(ws + R_OFF(c) + cell0, rr[0][c]);
        }
        if (hE && !pubRow){
          #pragma unroll
          for (int c=0;c<4;++c) stg1(ws + R_OFF(c) + cell0+1, rr[1][c]);
        }
        {
          float m4[4];
          #pragma unroll
          for (int c=0;c<4;++c)
            m4[c] = rr[0][c]*rr[0][c] + rr[1][c]*rr[1][c];
          #pragma unroll
          for (int m=0;m<4;++m){
            float v=m4[m];
            #pragma unroll
            for (int off=32; off; off>>=1) v += __shfl_xor(v, off);
            m4[m]=v;
          }
          if (lane==0){
            #pragma unroll
            for (int m=0;m<4;++m) wRed[wv][m]=m4[m];
          }
          __syncthreads();
          if (tid<2){
            float s0=0.f, s1=0.f;
            #pragma unroll
            for (int w=0;w<8;++w){ s0 += wRed[w][2*tid]; s1 += wRed[w][2*tid+1]; }
            stg2(parts + bid*16 + 8 + 2*tid, make_float2(s0,s1));
          }
        }
        gsync_red<4,8>(wsi, parts, scalB, sRed+8, bid, tid, 2*g+2);
        #pragma unroll
        for (int c=0;c<4;++c){
          beta[c] = sRed[8+c]/rs[c];
          rs[c]   = sRed[8+c];
        }
        #pragma unroll
        for (int k=0;k<2;++k)
        #pragma unroll
        for (int c=0;c<4;++c) pold[k][c]=pn[k][c];
      } else {
        // ---- last iter: reaction (block-local), publish next-step b ----
        #pragma unroll
        for (int k=0;k<2;++k){
          float vv[4] = {xx[k][0], xx[k][1], xx[k][2], xx[k][3]};
          float o[4];
          mlp_all(sW, vv, o);
          #pragma unroll
          for (int c=0;c<4;++c) xnew[k][c] = xx[k][c] + DTf*tanhf(o[c]);
        }
        if (step < NSTEPS-1){
          if (pubRow){
            #pragma unroll
            for (int c=0;c<4;++c)
              stg2(ws + R_OFF(c) + cell0,
                   make_float2(gam[c]*xnew[0][c], gam[c]*xnew[1][c]));
          }
          if (hW && !pubRow){
            #pragma unroll
            for (int c=0;c<4;++c) stg1(ws + R_OFF(c) + cell0, gam[c]*xnew[0][c]);
          }
          if (hE && !pubRow){
            #pragma unroll
            for (int c=0;c<4;++c) stg1(ws + R_OFF(c) + cell0+1, gam[c]*xnew[1][c]);
          }
          gsync(wsi, bid, tid, 2*g+2);   // folded step-boundary sync
        } else {
          ((float4*)out)[cell0]   = make_float4(xnew[0][0],xnew[0][1],xnew[0][2],xnew[0][3]);
          ((float4*)out)[cell0+1] = make_float4(xnew[1][0],xnew[1][1],xnew[1][2],xnew[1][3]);
        }
      }
    }
  }
}

// diagnostic: runs ONLY if ws is too small — absmax ≈ 54321 signals that.
__global__ void diag_ws(float* out){ out[0] = 54321.0f; }

extern "C" void kernel_launch(void* const* d_in, const int* in_sizes, int n_in,
                              void* d_out, int out_size, void* d_ws, size_t ws_size,
                              hipStream_t stream) {
  const float* U0    = (const float*)d_in[0];
  const float* scale = (const float*)d_in[1];
  const float* K1    = (const float*)d_in[2];
  const float* K2    = (const float*)d_in[3];
  const float* K3    = (const float*)d_in[4];
  float* out = (float*)d_out;
  float* ws  = (float*)d_ws;

  const size_t need = (size_t)(CTRL_FLOATS + 4*NNg) * sizeof(float);
  if (ws_size < need) {
    hipLaunchKernelGGL(diag_ws, dim3(1), dim3(1), 0, stream, out);
    return;
  }
  // zero flags + release lines + scalars + parts (harness poisons ws with 0xAA)
  hipMemsetAsync(ws, 0, CTRL_FLOATS*sizeof(float), stream);
  hipLaunchKernelGGL(drk, dim3(NBT), dim3(TPB), 0, stream,
                     U0, scale, K1, K2, K3, out, ws);
}

// Round 15
// 1429.729 us; speedup vs baseline: 2.2129x; 2.2129x over previous
//
#include <hip/hip_runtime.h>

#define NXg 512
#define NYg 512
#define NNg (NXg*NYg)
#define TPB 512
#define NBT 256
#define NSTEPS 8
#define CGIT 10
#define DTf (1.0f/64.0f)
#define H2I 256.0f

// ws float layout — all cross-block via relaxed AGENT (sc1) atomics (r13 transport).
//  [b*16 + 0..11]   12 partials {rs[4], rw[4], rA[4]} ; [b*16+12] tag (int)
//  [4096]           release gen (int) ; [4098..4106) alpha[4],beta[4]
//  [8192 ..)        W[2 par][4 ch][NNg] | B[4 ch][NNg]
#define RELGEN 4096
#define SCAL   4098
#define CTRL_FLOATS 8192
#define W_OFF(par,c) (CTRL_FLOATS + ((par)*4+(c))*NNg)
#define B_OFF(c)     (CTRL_FLOATS + (8+(c))*NNg)

__device__ __forceinline__ int ld_flag(int* p){
  return __hip_atomic_load(p, __ATOMIC_RELAXED, __HIP_MEMORY_SCOPE_AGENT);
}
__device__ __forceinline__ void st_flag(int* p, int v){
  __hip_atomic_store(p, v, __ATOMIC_RELAXED, __HIP_MEMORY_SCOPE_AGENT);
}
union F2U { unsigned long long u; float2 f; };
__device__ __forceinline__ float2 ldg2(float* p){
  F2U t; t.u = __hip_atomic_load((unsigned long long*)p, __ATOMIC_RELAXED, __HIP_MEMORY_SCOPE_AGENT);
  return t.f;
}
__device__ __forceinline__ void stg2(float* p, float2 v){
  F2U t; t.f = v;
  __hip_atomic_store((unsigned long long*)p, t.u, __ATOMIC_RELAXED, __HIP_MEMORY_SCOPE_AGENT);
}

__device__ __forceinline__ void mlp_all(const float* sW, const float* vv, float* o){
  float h1[16];
  #pragma unroll
  for (int h=0;h<16;++h)
    h1[h] = tanhf(vv[0]*sW[h]+vv[1]*sW[16+h]+vv[2]*sW[32+h]+vv[3]*sW[48+h]);
  o[0]=o[1]=o[2]=o[3]=0.f;
  #pragma unroll
  for (int j=0;j<16;++j){
    float s=0.f;
    #pragma unroll
    for (int h=0;h<16;++h) s += h1[h]*sW[64+16*h+j];
    const float t = tanhf(s);
    o[0]+=t*sW[320+4*j+0]; o[1]+=t*sW[320+4*j+1];
    o[2]+=t*sW[320+4*j+2]; o[3]+=t*sW[320+4*j+3];
  }
}

__global__ void __launch_bounds__(TPB)
drk(const float* __restrict__ U0, const float* __restrict__ scale,
    const float* __restrict__ K1, const float* __restrict__ K2,
    const float* __restrict__ K3, float* __restrict__ out,
    float* __restrict__ ws)
{
  __shared__ float sW[384];
  __shared__ float sP[2][4][NXg];   // r tile, 16 KB
  __shared__ float wRed[8][12];
  __shared__ float sAB[8];          // alpha[4], beta[4]

  const int tid=threadIdx.x, bid=blockIdx.x;
  const int r    = tid>>8;          // row in block: 0/1
  const int lane = tid&63;
  const int wv   = tid>>6;          // wave 0..7
  const int c2   = (tid&255)*2;     // column base (2 cells/thread)
  const int grow = bid*2 + r;
  const int cell0= grow*NXg + c2;
  const bool hUp = (r==0) && (grow>0);
  const bool hDn = (r==1) && (grow<NYg-1);
  const bool hasHalo = hUp || hDn;
  const int hrow = (r==0) ? (grow-1) : (grow+1);

  if (tid < 384){
    float w;
    if (tid < 64)       w = K1[tid];
    else if (tid < 320) w = K2[tid-64];
    else                w = K3[tid-320];
    sW[tid]=w;
  }
  __syncthreads();

  int* wsi = (int*)ws;
  float gam[4];
  #pragma unroll
  for (int c=0;c<4;++c) gam[c] = 1.0f/(scale[c]*DTf);

  float xnew[2][4];
  {
    const float4 u0 = ((const float4*)U0)[cell0];
    const float4 u1 = ((const float4*)U0)[cell0+1];
    xnew[0][0]=u0.x; xnew[0][1]=u0.y; xnew[0][2]=u0.z; xnew[0][3]=u0.w;
    xnew[1][0]=u1.x; xnew[1][1]=u1.y; xnew[1][2]=u1.z; xnew[1][3]=u1.w;
  }

  // master state (meaningful only in bid 0, wave 0; uniform across its lanes)
  float rs_prev[4]={0,0,0,0}, pAp_prev[4]={0,0,0,0};

  for (int step=0; step<NSTEPS; ++step){
    float rr[2][4], xx[2][4], pp[2][4], Ap[2][4];
    float rh[2][4], Aph[2][4];
    #pragma unroll
    for (int c=0;c<4;++c)
    #pragma unroll
    for (int k=0;k<2;++k){
      rr[k][c] = gam[c]*xnew[k][c];
      xx[k][c]=0.f; pp[k][c]=0.f; Ap[k][c]=0.f; Aph[k][c]=0.f; rh[k][c]=0.f;
    }
    // halo r mirror bootstrap
    if (hasHalo){
      if (step==0){
        const float4 h0 = ((const float4*)U0)[hrow*NXg + c2];
        const float4 h1 = ((const float4*)U0)[hrow*NXg + c2+1];
        rh[0][0]=gam[0]*h0.x; rh[0][1]=gam[1]*h0.y; rh[0][2]=gam[2]*h0.z; rh[0][3]=gam[3]*h0.w;
        rh[1][0]=gam[0]*h1.x; rh[1][1]=gam[1]*h1.y; rh[1][2]=gam[2]*h1.z; rh[1][3]=gam[3]*h1.w;
      } else {
        #pragma unroll
        for (int c=0;c<4;++c){
          const float2 h = ldg2(ws + B_OFF(c) + hrow*NXg + c2);  // = gam*xnew_h
          rh[0][c]=h.x; rh[1][c]=h.y;
        }
      }
    }

    for (int it=0; it<CGIT; ++it){
      const int tgt = step*11 + it + 1;
      const int par = it&1;

      // ---- tile r; stencil w = A r ----
      #pragma unroll
      for (int k=0;k<2;++k)
      #pragma unroll
      for (int c=0;c<4;++c) sP[r][c][c2+k] = rr[k][c];
      __syncthreads();

      float w[2][4];
      #pragma unroll
      for (int c=0;c<4;++c)
      #pragma unroll
      for (int k=0;k<2;++k){
        const int col = c2+k;
        const float u = rr[k][c];
        float s = 0.f;
        if (r==1) s += u - sP[0][c][col]; else if (grow>0)     s += u - rh[k][c];
        if (r==0) s += u - sP[1][c][col]; else if (grow<NYg-1) s += u - rh[k][c];
        if (col > 0)     s += u - ((k==1) ? rr[0][c] : sP[r][c][col-1]);
        if (col < NXg-1) s += u - ((k==0) ? rr[1][c] : sP[r][c][col+1]);
        w[k][c] = s*H2I + gam[c]*u;
      }
      // publish boundary w (parity-buffered) — skipped on last iter
      if (hasHalo && it < CGIT-1){
        #pragma unroll
        for (int c=0;c<4;++c)
          stg2(ws + W_OFF(par,c) + grow*NXg + c2, make_float2(w[0][c],w[1][c]));
      }

      // ---- direct dots {rs, rw, rA} ----
      float m12[12];
      #pragma unroll
      for (int c=0;c<4;++c){
        float rs_l=0.f, rw_l=0.f, rA_l=0.f;
        #pragma unroll
        for (int k=0;k<2;++k){
          rs_l += rr[k][c]*rr[k][c];
          rw_l += rr[k][c]*w[k][c];
          rA_l += rr[k][c]*Ap[k][c];
        }
        m12[c]=rs_l; m12[4+c]=rw_l; m12[8+c]=rA_l;
      }
      #pragma unroll
      for (int m=0;m<12;++m){
        float v=m12[m];
        #pragma unroll
        for (int off=32; off; off>>=1) v += __shfl_xor(v, off);
        m12[m]=v;
      }
      if (lane==0){
        #pragma unroll
        for (int m=0;m<12;++m) wRed[wv][m]=m12[m];
      }
      asm volatile("s_waitcnt vmcnt(0)" ::: "memory");  // drain w publishes
      __syncthreads();

      // wave 0: fold, store partials + tag (arrival)
      if (wv==0){
        float s=0.f;
        if (lane<12){
          #pragma unroll
          for (int q=0;q<8;++q) s += wRed[q][lane];
        }
        const float s0 = __shfl(s, 2*lane);
        const float s1 = __shfl(s, 2*lane+1);
        if (lane<6) stg2(ws + bid*16 + 2*lane, make_float2(s0,s1));
        asm volatile("s_waitcnt vmcnt(0)" ::: "memory");
        if (lane==0) st_flag(&wsi[bid*16+12], tgt);
      }

      // ---- single sync: master gathers, computes alpha/beta, broadcasts ----
      if (bid==0 && tid<64){
        const int b0 = tid*4;
        int ok=0;
        while(!ok){
          int m=1;
          #pragma unroll
          for (int j=0;j<4;++j) m &= (ld_flag(&wsi[(b0+j)*16+12]) >= tgt);
          ok=__all(m);
          if(!ok) __builtin_amdgcn_s_sleep(1);
        }
        float mm[12];
        #pragma unroll
        for (int m=0;m<12;++m) mm[m]=0.f;
        #pragma unroll
        for (int j=0;j<4;++j)
          #pragma unroll
          for (int t=0;t<6;++t){
            const float2 v = ldg2(ws + (b0+j)*16 + 2*t);
            mm[2*t] += v.x; mm[2*t+1] += v.y;
          }
        #pragma unroll
        for (int m=0;m<12;++m){
          float v=mm[m];
          #pragma unroll
          for (int off=32; off; off>>=1) v += __shfl_xor(v, off);
          mm[m]=v;
        }
        float aR[4], bR[4];
        #pragma unroll
        for (int c=0;c<4;++c){
          const float rsv=mm[c], rwv=mm[4+c], rAv=mm[8+c];
          const float bet = (it==0) ? 0.f
                          : ((rs_prev[c] > 0.f) ? rsv/rs_prev[c] : 0.f);
          const float pap = rwv + 2.f*bet*rAv + bet*bet*pAp_prev[c];
          const float alp = (rsv > 0.f && pap > 0.f) ? rsv/pap : 0.f;
          rs_prev[c]=rsv; pAp_prev[c]=pap;
          aR[c]=alp; bR[c]=bet;
        }
        if (tid==0){
          stg2(ws+SCAL+0, make_float2(aR[0],aR[1]));
          stg2(ws+SCAL+2, make_float2(aR[2],aR[3]));
          stg2(ws+SCAL+4, make_float2(bR[0],bR[1]));
          stg2(ws+SCAL+6, make_float2(bR[2],bR[3]));
          asm volatile("s_waitcnt vmcnt(0)" ::: "memory");
          st_flag(&wsi[RELGEN], tgt);
          #pragma unroll
          for (int c=0;c<4;++c){ sAB[c]=aR[c]; sAB[4+c]=bR[c]; }
        }
      } else if (bid!=0 && tid==0){
        while(ld_flag(&wsi[RELGEN]) < tgt) __builtin_amdgcn_s_sleep(1);
        const float2 a01=ldg2(ws+SCAL+0), a23=ldg2(ws+SCAL+2);
        const float2 b01=ldg2(ws+SCAL+4), b23=ldg2(ws+SCAL+6);
        sAB[0]=a01.x; sAB[1]=a01.y; sAB[2]=a23.x; sAB[3]=a23.y;
        sAB[4]=b01.x; sAB[5]=b01.y; sAB[6]=b23.x; sAB[7]=b23.y;
      }
      __syncthreads();
      float alpha[4], beta[4];
      #pragma unroll
      for (int c=0;c<4;++c){ alpha[c]=sAB[c]; beta[c]=sAB[4+c]; }

      // ---- updates: p = r + b p; Ap = w + b Ap; x += a p; r -= a Ap ----
      #pragma unroll
      for (int k=0;k<2;++k)
      #pragma unroll
      for (int c=0;c<4;++c){
        pp[k][c] = rr[k][c] + beta[c]*pp[k][c];
        Ap[k][c] = w[k][c]  + beta[c]*Ap[k][c];
        xx[k][c] += alpha[c]*pp[k][c];
      }
      if (it < CGIT-1){
        #pragma unroll
        for (int k=0;k<2;++k)
        #pragma unroll
        for (int c=0;c<4;++c) rr[k][c] -= alpha[c]*Ap[k][c];
        // mirrors: Ap_h = w_h + b Ap_h ; r_h -= a Ap_h  (bit-identical to neighbor)
        if (hasHalo){
          #pragma unroll
          for (int c=0;c<4;++c){
            const float2 hw = ldg2(ws + W_OFF(par,c) + hrow*NXg + c2);
            Aph[0][c] = hw.x + beta[c]*Aph[0][c];
            Aph[1][c] = hw.y + beta[c]*Aph[1][c];
            rh[0][c] -= alpha[c]*Aph[0][c];
            rh[1][c] -= alpha[c]*Aph[1][c];
          }
        }
      }
      __syncthreads();   // protect sP/wRed/sAB WAR before next iteration
    }

    // ---- reaction (block-local) ----
    #pragma unroll
    for (int k=0;k<2;++k){
      float vv[4] = {xx[k][0], xx[k][1], xx[k][2], xx[k][3]};
      float o[4];
      mlp_all(sW, vv, o);
      #pragma unroll
      for (int c=0;c<4;++c) xnew[k][c] = xx[k][c] + DTf*tanhf(o[c]);
    }

    if (step < NSTEPS-1){
      // publish next-step b (= gam*xnew) boundary rows, then step sync
      const int tgt = step*11 + 11;
      if (hasHalo){
        #pragma unroll
        for (int c=0;c<4;++c)
          stg2(ws + B_OFF(c) + grow*NXg + c2,
               make_float2(gam[c]*xnew[0][c], gam[c]*xnew[1][c]));
      }
      asm volatile("s_waitcnt vmcnt(0)" ::: "memory");
      __syncthreads();
      if (tid==0) st_flag(&wsi[bid*16+12], tgt);
      if (bid==0 && tid<64){
        const int b0 = tid*4;
        int ok=0;
        while(!ok){
          int m=1;
          #pragma unroll
          for (int j=0;j<4;++j) m &= (ld_flag(&wsi[(b0+j)*16+12]) >= tgt);
          ok=__all(m);
          if(!ok) __builtin_amdgcn_s_sleep(1);
        }
        if (tid==0) st_flag(&wsi[RELGEN], tgt);
      } else if (bid!=0 && tid==0){
        while(ld_flag(&wsi[RELGEN]) < tgt) __builtin_amdgcn_s_sleep(1);
      }
      __syncthreads();
    } else {
      ((float4*)out)[cell0]   = make_float4(xnew[0][0],xnew[0][1],xnew[0][2],xnew[0][3]);
      ((float4*)out)[cell0+1] = make_float4(xnew[1][0],xnew[1][1],xnew[1][2],xnew[1][3]);
    }
  }
}

// diagnostic: runs ONLY if ws is too small — absmax ≈ 54321 signals that.
__global__ void diag_ws(float* out){ out[0] = 54321.0f; }

extern "C" void kernel_launch(void* const* d_in, const int* in_sizes, int n_in,
                              void* d_out, int out_size, void* d_ws, size_t ws_size,
                              hipStream_t stream) {
  const float* U0    = (const float*)d_in[0];
  const float* scale = (const float*)d_in[1];
  const float* K1    = (const float*)d_in[2];
  const float* K2    = (const float*)d_in[3];
  const float* K3    = (const float*)d_in[4];
  float* out = (float*)d_out;
  float* ws  = (float*)d_ws;

  const size_t need = (size_t)(CTRL_FLOATS + 12*NNg) * sizeof(float);
  if (ws_size < need) {
    hipLaunchKernelGGL(diag_ws, dim3(1), dim3(1), 0, stream, out);
    return;
  }
  // zero tags + release + scalars (harness poisons ws with 0xAA)
  hipMemsetAsync(ws, 0, CTRL_FLOATS*sizeof(float), stream);
  hipLaunchKernelGGL(drk, dim3(NBT), dim3(TPB), 0, stream,
                     U0, scale, K1, K2, K3, out, ws);
}